// Round 6
// baseline (28050.067 us; speedup 1.0000x reference)
//
#include <hip/hip_runtime.h>
#include <hip/hip_bf16.h>

#define H_ 1024
#define C_ 1536
#define B_ 256
#define T_ 128
#define IN_ 512
#define BH_ (B_*H_)
#define NBLK 704

typedef __hip_bfloat16 bf16;
typedef __attribute__((ext_vector_type(8))) short short8;
typedef __attribute__((ext_vector_type(4))) float f32x4;
typedef unsigned int u32;

struct WPtrs { const float* W[10]; const float* wA; };
struct BPtrs { const float* b[10]; const float* bA[4]; };

__device__ __forceinline__ float sigmf(float x){ return 1.0f/(1.0f + __expf(-x)); }
__device__ __forceinline__ float tanhfast(float x){ return 1.0f - 2.0f/(__expf(2.0f*x) + 1.0f); }

__device__ __forceinline__ ushort bf16bits(float f){
    bf16 b = __float2bfloat16(f);
    return *reinterpret_cast<ushort*>(&b);
}

// async global->LDS, 16B per lane; lds dest is wave-uniform base (+lane*16 by HW)
__device__ __forceinline__ void gload16(const void* g, void* l){
    __builtin_amdgcn_global_load_lds((const __attribute__((address_space(1))) u32*)g,
                                     (__attribute__((address_space(3))) u32*)l, 16, 0, 0);
}

// ---- weight transpose+convert: src fp32 [K][H] -> dst bf16 [H][K]
__global__ void transpose_w(WPtrs wp, ushort* __restrict__ Wt, ushort* __restrict__ wAt)
{
    int g = blockIdx.z;
    int K = (g==10) ? H_ : C_;
    int k0 = blockIdx.x*32, n0 = blockIdx.y*32;
    if (k0 >= K) return;
    const float* src = (g==10) ? wp.wA : wp.W[g];
    __shared__ float tile[32][33];
    int tx = threadIdx.x, ty = threadIdx.y;
    #pragma unroll
    for (int i=0;i<32;i+=8)
        tile[ty+i][tx] = src[(size_t)(k0+ty+i)*H_ + n0 + tx];
    __syncthreads();
    ushort* dst = (g==10) ? wAt : (Wt + (size_t)g*H_*C_);
    #pragma unroll
    for (int i=0;i<32;i+=8)
        dst[(size_t)(n0+ty+i)*K + k0 + tx] = bf16bits(tile[tx][ty+i]);
}

// ---- x fp32 -> bf16, all 4 factor arrays
__global__ void convert_x(const float* __restrict__ xY, const float* __restrict__ xI,
                          const float* __restrict__ xP, const float* __restrict__ xN,
                          ushort* __restrict__ xb)
{
    size_t idx = (size_t)blockIdx.x*blockDim.x + threadIdx.x;
    size_t base = idx*4;
    size_t a = base >> 24;
    size_t off = base & ((size_t)(1u<<24)-1);
    const float* s = (a==0)?xY:(a==1)?xI:(a==2)?xP:xN;
    float4 v = *(const float4*)(s + off);
    ushort4 o;
    o.x = bf16bits(v.x); o.y = bf16bits(v.y); o.z = bf16bits(v.z); o.w = bf16bits(v.w);
    *(ushort4*)(xb + base) = o;
}

// ---- grid barrier: 16 spread counters, monotonic phase targets, device scope.
__device__ __forceinline__ void gbarrier(u32* cnts, int bid, u32 phase)
{
    __threadfence();                 // release: every thread's stores
    __syncthreads();
    if (threadIdx.x == 0){
        __hip_atomic_fetch_add(&cnts[(bid & 15) << 6], 1u,
                               __ATOMIC_RELAXED, __HIP_MEMORY_SCOPE_AGENT);
        u32 target = (u32)NBLK * phase;
        for (;;){
            u32 s = 0;
            #pragma unroll
            for (int i=0;i<16;++i)
                s += __hip_atomic_load(&cnts[i<<6], __ATOMIC_RELAXED, __HIP_MEMORY_SCOPE_AGENT);
            if (s >= target) break;
            __builtin_amdgcn_s_sleep(1);
        }
    }
    __syncthreads();
    __threadfence();                 // acquire
}

// ---- persistent kernel: whole T-loop. 704 blocks x 128 threads (2 waves).
// Per step: phase A = split-K GEMM (same geometry as before: 8 XCD x 11 ntile(128)
// x 4 mtile(64) x 2 ksplit), grid barrier, phase B = per-row update on blocks 0..255,
// grid barrier. Cell state c lives in registers of the update block.
__global__ __launch_bounds__(128, 2) void persist(
    const ushort* __restrict__ Wt, const ushort* __restrict__ wAt,
    const ushort* __restrict__ xb, ushort* __restrict__ hb,
    ushort* __restrict__ cbuf, float* __restrict__ P,
    BPtrs bp, float* __restrict__ out, u32* __restrict__ cnts)
{
    int bid = blockIdx.x;
    int xcd = bid & 7, lid = bid >> 3;     // lid in [0,88)
    int ntile = xcd*11 + (lid >> 3);       // [0,88)
    int rem = lid & 7;
    int mtile = rem >> 1;                  // [0,4)
    int split = rem & 1;                   // [0,2)
    int nglob0 = ntile*128;
    int g = nglob0 >> 10;
    int n0g = nglob0 & 1023;
    int m0 = mtile*64;
    bool isA = (g==10);
    const ushort* Bbase = isA ? wAt : (Wt + (size_t)g*H_*C_);
    size_t Bstride = isA ? 1024 : 1536;
    int kStart = isA ? split*512 : split*768;
    int kEnd   = isA ? kStart+512 : kStart+768;
    int xs = (g==3)?1:(g==4)?2:(g==5)?3:0;
    const ushort* xsrc = xb + (size_t)xs*((size_t)B_*T_*IN_);
    const ushort* Ah = isA ? cbuf : hb;

    __shared__ ushort As[2][64*64];
    __shared__ ushort Bs[2][128*64];
    int tid = threadIdx.x;
    int wid = tid>>6, lane = tid&63;

    // registers for update phase (block bid<256 owns row bid forever)
    float creg[8];
    #pragma unroll
    for (int q=0;q<8;++q) creg[q] = 0.f;

    for (int t=0; t<T_; ++t){
        // ================= phase A: GEMM =================
        {
            auto stage = [&](int buf, int k0){
                ushort* la = As[buf];
                ushort* lb = Bs[buf];
                #pragma unroll
                for (int it=0; it<4; ++it){        // A: 512 slots
                    int cid = it*128 + tid;
                    int row = cid>>3, kc = cid&7;
                    int kcs = kc ^ (row&7);
                    int k = k0 + kcs*8;
                    const ushort* src;
                    if (isA || k < 1024) src = Ah + (size_t)(m0+row)*H_ + k;
                    else                 src = xsrc + ((size_t)(m0+row)*T_ + t)*IN_ + (k-1024);
                    gload16(src, la + (size_t)(it*128 + wid*64)*8);
                }
                #pragma unroll
                for (int it=0; it<8; ++it){        // B: 1024 slots
                    int cid = it*128 + tid;
                    int row = cid>>3, kc = cid&7;
                    int kcs = kc ^ (row&7);
                    gload16(Bbase + (size_t)(n0g+row)*Bstride + k0 + kcs*8,
                            lb + (size_t)(it*128 + wid*64)*8);
                }
            };

            f32x4 acc[4][4] = {};
            stage(0, kStart);
            __syncthreads();

            int nIter = (kEnd - kStart) >> 6;
            for (int i=0; i<nIter; ++i){
                int cur = i & 1;
                if (i+1 < nIter) stage(cur^1, kStart + ((i+1)<<6));
                ushort* la = As[cur];
                ushort* lb = Bs[cur];
                #pragma unroll
                for (int kk=0; kk<2; ++kk){
                    short8 af[4], bfr[4];
                    #pragma unroll
                    for (int mr=0;mr<4;++mr){
                        int r = mr*16 + (lane&15);
                        int j = (kk*4 + (lane>>4)) ^ (r&7);
                        af[mr] = *(const short8*)(la + r*64 + j*8);
                    }
                    #pragma unroll
                    for (int nr=0;nr<4;++nr){
                        int r = wid*64 + nr*16 + (lane&15);
                        int j = (kk*4 + (lane>>4)) ^ (r&7);
                        bfr[nr] = *(const short8*)(lb + r*64 + j*8);
                    }
                    #pragma unroll
                    for (int mr=0;mr<4;++mr)
                        #pragma unroll
                        for (int nr=0;nr<4;++nr)
                            acc[mr][nr] = __builtin_amdgcn_mfma_f32_16x16x32_bf16(af[mr], bfr[nr], acc[mr][nr], 0,0,0);
                }
                __syncthreads();
            }

            float* Pg = P + ((size_t)split*11 + g)*BH_;
            #pragma unroll
            for (int mr=0;mr<4;++mr){
                #pragma unroll
                for (int nr=0;nr<4;++nr){
                    int col = n0g + wid*64 + nr*16 + (lane&15);
                    #pragma unroll
                    for (int r=0;r<4;++r){
                        int rowg = m0 + mr*16 + (lane>>4)*4 + r;
                        Pg[(size_t)rowg*H_ + col] = acc[mr][nr][r];
                    }
                }
            }
        }
        gbarrier(cnts, bid, (u32)(2*t+1));

        // ================= phase B: update (blocks 0..255) =================
        if (bid < B_){
            int b = bid;
            const float* Pb = P + (size_t)b*H_;
            float lY[8], lI[8], lPv[8], lN[8], fv[8], ov[8];
            float v0=0,v1=0,v2=0,v3=0;
            #pragma unroll
            for (int q=0;q<8;++q){
                int j = tid + q*128;
                float g0 = Pb[(size_t)0*BH_+j]  + Pb[(size_t)11*BH_+j];
                float g1 = Pb[(size_t)1*BH_+j]  + Pb[(size_t)12*BH_+j];
                float g2 = Pb[(size_t)2*BH_+j]  + Pb[(size_t)13*BH_+j];
                float g3 = Pb[(size_t)3*BH_+j]  + Pb[(size_t)14*BH_+j];
                float g4 = Pb[(size_t)4*BH_+j]  + Pb[(size_t)15*BH_+j];
                float g5 = Pb[(size_t)5*BH_+j]  + Pb[(size_t)16*BH_+j];
                float g6 = Pb[(size_t)6*BH_+j]  + Pb[(size_t)17*BH_+j];
                float g7 = Pb[(size_t)7*BH_+j]  + Pb[(size_t)18*BH_+j];
                float g8 = Pb[(size_t)8*BH_+j]  + Pb[(size_t)19*BH_+j];
                float g9 = Pb[(size_t)9*BH_+j]  + Pb[(size_t)20*BH_+j];
                float gA = Pb[(size_t)10*BH_+j] + Pb[(size_t)21*BH_+j];
                fv[q] = sigmf(g0 + bp.b[0][j]);
                ov[q] = sigmf(g1 + bp.b[1][j]);
                lY[q]  = tanhfast(g2 + bp.b[2][j]) * sigmf(g6 + bp.b[6][j]);
                lI[q]  = tanhfast(g3 + bp.b[3][j]) * sigmf(g7 + bp.b[7][j]);
                lPv[q] = tanhfast(g4 + bp.b[4][j]) * sigmf(g8 + bp.b[8][j]);
                lN[q]  = tanhfast(g5 + bp.b[5][j]) * sigmf(g9 + bp.b[9][j]);
                v0 += lY[q]*gA; v1 += lI[q]*gA; v2 += lPv[q]*gA; v3 += lN[q]*gA;
            }
            #pragma unroll
            for (int d=32; d>=1; d>>=1){
                v0 += __shfl_down(v0,d); v1 += __shfl_down(v1,d);
                v2 += __shfl_down(v2,d); v3 += __shfl_down(v3,d);
            }
            float* red = (float*)&As[0][0];
            if (lane==0){ red[wid*4+0]=v0; red[wid*4+1]=v1; red[wid*4+2]=v2; red[wid*4+3]=v3; }
            __syncthreads();
            float sY = red[0]+red[4];
            float sI = red[1]+red[5];
            float sP = red[2]+red[6];
            float sN = red[3]+red[7];

            float zp = 0.f;
            #pragma unroll
            for (int q=0;q<8;++q){
                int j = tid + q*128;
                zp += __expf(tanhfast(sY + bp.bA[0][j]));
                zp += __expf(tanhfast(sI + bp.bA[1][j]));
                zp += __expf(tanhfast(sP + bp.bA[2][j]));
                zp += __expf(tanhfast(sN + bp.bA[3][j]));
            }
            #pragma unroll
            for (int d=32; d>=1; d>>=1) zp += __shfl_down(zp,d);
            float* zred = red + 8;
            if (lane==0) zred[wid] = zp;
            __syncthreads();
            float Z = zred[0]+zred[1];
            float Zi = 1.0f / Z;
            float a0 = __expf(tanhfast(sY + bp.bA[0][0]))*Zi;
            float a1 = __expf(tanhfast(sY + bp.bA[0][1]))*Zi;
            float a2 = __expf(tanhfast(sY + bp.bA[0][2]))*Zi;
            float a3 = __expf(tanhfast(sY + bp.bA[0][3]))*Zi;

            #pragma unroll
            for (int q=0;q<8;++q){
                int j = tid + q*128;
                float lT = a0*lY[q] + a1*lI[q] + a2*lPv[q] + a3*lN[q];
                float cn = creg[q]*fv[q] + lT;
                creg[q] = cn;
                cbuf[(size_t)b*H_ + j] = bf16bits(cn);
                float hn = tanhfast(cn)*ov[q];
                hb[(size_t)b*H_ + j] = bf16bits(hn);
                out[((size_t)b*T_ + t)*H_ + j] = hn;
            }
        }
        if (t < T_-1) gbarrier(cnts, bid, (u32)(2*t+2));
    }
}

extern "C" void kernel_launch(void* const* d_in, const int* in_sizes, int n_in,
                              void* d_out, int out_size, void* d_ws, size_t ws_size,
                              hipStream_t stream)
{
    WPtrs wp; BPtrs bp;
    for (int i=0;i<10;++i){ wp.W[i] = (const float*)d_in[2*i]; bp.b[i] = (const float*)d_in[2*i+1]; }
    wp.wA = (const float*)d_in[20];
    for (int i=0;i<4;++i) bp.bA[i] = (const float*)d_in[21+i];
    const float* xY = (const float*)d_in[25];
    const float* xI = (const float*)d_in[26];
    const float* xP = (const float*)d_in[27];
    const float* xN = (const float*)d_in[28];

    char* w = (char*)d_ws;
    size_t off = 0;
    ushort* Wt  = (ushort*)(w+off); off += (size_t)10*H_*C_*2;        // 31.46 MB
    ushort* wAt = (ushort*)(w+off); off += (size_t)H_*H_*2;           // 2 MB
    ushort* xb  = (ushort*)(w+off); off += (size_t)4*B_*T_*IN_*2;     // 134.2 MB
    float*  P   = (float*)(w+off);  off += (size_t)22*BH_*4;          // 23 MB
    ushort* hb  = (ushort*)(w+off); off += (size_t)BH_*2;             // 0.5 MB
    ushort* cbuf= (ushort*)(w+off); off += (size_t)BH_*2;             // 0.5 MB
    u32*    cnts= (u32*)(w+off);    off += 16*64*4;                   // 4 KB

    // zero hb, cbuf, barrier counters (contiguous)
    hipMemsetAsync(hb, 0, (size_t)4*BH_ + 16*64*4, stream);

    transpose_w<<<dim3(C_/32, H_/32, 11), dim3(32,8), 0, stream>>>(wp, Wt, wAt);
    convert_x<<<(4u*B_*T_*IN_/4)/256, 256, 0, stream>>>(xY,xI,xP,xN, xb);

    persist<<<NBLK, 128, 0, stream>>>(Wt, wAt, xb, hb, cbuf, P, bp, (float*)d_out, cnts);
}

// Round 7
// 13305.374 us; speedup vs baseline: 2.1082x; 2.1082x over previous
//
#include <hip/hip_runtime.h>
#include <hip/hip_bf16.h>

#define H_ 1024
#define C_ 1536
#define B_ 256
#define T_ 128
#define IN_ 512
#define BH_ (B_*H_)
#define NBLK 704

typedef __hip_bfloat16 bf16;
typedef __attribute__((ext_vector_type(8))) short short8;
typedef __attribute__((ext_vector_type(4))) float f32x4;
typedef unsigned int u32;
typedef unsigned long long u64;

struct WPtrs { const float* W[10]; const float* wA; };
struct BPtrs { const float* b[10]; const float* bA[4]; };

__device__ __forceinline__ float sigmf(float x){ return 1.0f/(1.0f + __expf(-x)); }
__device__ __forceinline__ float tanhfast(float x){ return 1.0f - 2.0f/(__expf(2.0f*x) + 1.0f); }

__device__ __forceinline__ ushort bf16bits(float f){
    bf16 b = __float2bfloat16(f);
    return *reinterpret_cast<ushort*>(&b);
}
__device__ __forceinline__ float bf2f(ushort u){
    bf16 b = *reinterpret_cast<bf16*>(&u);
    return __bfloat162float(b);
}

// ---- coherent (cross-XCD) access helpers: relaxed agent-scope atomics.
// These bypass the non-coherent per-XCD L2 path for mutable shared data,
// WITHOUT fences that would invalidate the whole L2 (weights stay cached).
__device__ __forceinline__ void astoref(float* p, float v){
    __hip_atomic_store(p, v, __ATOMIC_RELAXED, __HIP_MEMORY_SCOPE_AGENT);
}
__device__ __forceinline__ float aloadf(const float* p){
    return __hip_atomic_load(p, __ATOMIC_RELAXED, __HIP_MEMORY_SCOPE_AGENT);
}
__device__ __forceinline__ u64 aload64(const u64* p){
    return __hip_atomic_load(p, __ATOMIC_RELAXED, __HIP_MEMORY_SCOPE_AGENT);
}
__device__ __forceinline__ void astore64(u64* p, u64 v){
    __hip_atomic_store(p, v, __ATOMIC_RELAXED, __HIP_MEMORY_SCOPE_AGENT);
}

// async global->LDS, 16B per lane (cached path — weights only)
__device__ __forceinline__ void gload16(const void* g, void* l){
    __builtin_amdgcn_global_load_lds((const __attribute__((address_space(1))) u32*)g,
                                     (__attribute__((address_space(3))) u32*)l, 16, 0, 0);
}

// ---- weight transpose+convert: src fp32 [K][H] -> dst bf16 [H][K]
__global__ void transpose_w(WPtrs wp, ushort* __restrict__ Wt, ushort* __restrict__ wAt)
{
    int g = blockIdx.z;
    int K = (g==10) ? H_ : C_;
    int k0 = blockIdx.x*32, n0 = blockIdx.y*32;
    if (k0 >= K) return;
    const float* src = (g==10) ? wp.wA : wp.W[g];
    __shared__ float tile[32][33];
    int tx = threadIdx.x, ty = threadIdx.y;
    #pragma unroll
    for (int i=0;i<32;i+=8)
        tile[ty+i][tx] = src[(size_t)(k0+ty+i)*H_ + n0 + tx];
    __syncthreads();
    ushort* dst = (g==10) ? wAt : (Wt + (size_t)g*H_*C_);
    #pragma unroll
    for (int i=0;i<32;i+=8)
        dst[(size_t)(n0+ty+i)*K + k0 + tx] = bf16bits(tile[tx][ty+i]);
}

// ---- x fp32 -> bf16, all 4 factor arrays
__global__ void convert_x(const float* __restrict__ xY, const float* __restrict__ xI,
                          const float* __restrict__ xP, const float* __restrict__ xN,
                          ushort* __restrict__ xb)
{
    size_t idx = (size_t)blockIdx.x*blockDim.x + threadIdx.x;
    size_t base = idx*4;
    size_t a = base >> 24;
    size_t off = base & ((size_t)(1u<<24)-1);
    const float* s = (a==0)?xY:(a==1)?xI:(a==2)?xP:xN;
    float4 v = *(const float4*)(s + off);
    ushort4 o;
    o.x = bf16bits(v.x); o.y = bf16bits(v.y); o.z = bf16bits(v.z); o.w = bf16bits(v.w);
    *(ushort4*)(xb + base) = o;
}

// ---- grid barrier: 16 spread counters, monotonic phase targets.
// NO threadfence: ordering via per-wave vmcnt(0) drain (coherent stores are at
// the LLC once retired), then counter RMW at LLC.
__device__ __forceinline__ void gbarrier(u32* cnts, int bid, u32 phase)
{
    asm volatile("s_waitcnt vmcnt(0)" ::: "memory");
    __syncthreads();
    if (threadIdx.x == 0){
        __hip_atomic_fetch_add(&cnts[(bid & 15) << 6], 1u,
                               __ATOMIC_RELAXED, __HIP_MEMORY_SCOPE_AGENT);
        u32 target = (u32)NBLK * phase;
        for (;;){
            u32 s = 0;
            #pragma unroll
            for (int i=0;i<16;++i)
                s += __hip_atomic_load(&cnts[i<<6], __ATOMIC_RELAXED, __HIP_MEMORY_SCOPE_AGENT);
            if (s >= target) break;
            __builtin_amdgcn_s_sleep(2);
        }
    }
    __syncthreads();
}

// ---- persistent kernel: whole T-loop. 704 blocks x 128 threads (2 waves).
__global__ __launch_bounds__(128, 2) void persist(
    const ushort* __restrict__ Wt, const ushort* __restrict__ wAt,
    const ushort* __restrict__ xb, ushort* __restrict__ hb,
    ushort* __restrict__ cbuf, float* __restrict__ P,
    BPtrs bp, float* __restrict__ out, u32* __restrict__ cnts)
{
    int bid = blockIdx.x;
    int xcd = bid & 7, lid = bid >> 3;     // lid in [0,88)
    int ntile = xcd*11 + (lid >> 3);       // [0,88)
    int rem = lid & 7;
    int mtile = rem >> 1;                  // [0,4)
    int split = rem & 1;                   // [0,2)
    int nglob0 = ntile*128;
    int g = nglob0 >> 10;
    int n0g = nglob0 & 1023;
    int m0 = mtile*64;
    bool isA = (g==10);
    const ushort* Bbase = isA ? wAt : (Wt + (size_t)g*H_*C_);
    size_t Bstride = isA ? 1024 : 1536;
    int kStart = isA ? split*512 : split*768;
    int kEnd   = isA ? kStart+512 : kStart+768;
    int xs = (g==3)?1:(g==4)?2:(g==5)?3:0;
    const ushort* xsrc = xb + (size_t)xs*((size_t)B_*T_*IN_);
    const ushort* Ah = isA ? cbuf : hb;

    __shared__ ushort As[2][64*64];
    __shared__ ushort Bs[2][128*64];
    int tid = threadIdx.x;
    int wid = tid>>6, lane = tid&63;

    // cell state for update phase (block bid<256 owns row bid forever)
    float creg[8];
    #pragma unroll
    for (int q=0;q<8;++q) creg[q] = 0.f;

    for (int t=0; t<T_; ++t){
        // ================= phase A: GEMM =================
        {
            auto stage = [&](int buf, int k0){
                ushort* la = As[buf];
                ushort* lb = Bs[buf];
                // A-half: h/c (mutable, cross-XCD) -> coherent loads + ds_write.
                #pragma unroll
                for (int it=0; it<4; ++it){        // 512 slots x 16B
                    int cid = it*128 + tid;
                    int row = cid>>3, kc = cid&7;
                    int kcs = kc ^ (row&7);
                    int k = k0 + kcs*8;
                    const ushort* src;
                    if (isA || k < 1024) src = Ah + (size_t)(m0+row)*H_ + k;
                    else                 src = xsrc + ((size_t)(m0+row)*T_ + t)*IN_ + (k-1024);
                    const u64* s64 = (const u64*)src;
                    u64 d0 = aload64(s64);
                    u64 d1 = aload64(s64+1);
                    ulong2* dst = (ulong2*)(la + (size_t)cid*8);
                    ulong2 v; v.x = d0; v.y = d1;
                    *dst = v;
                }
                // B-half: weights (read-only) -> cached global_load_lds.
                #pragma unroll
                for (int it=0; it<8; ++it){        // 1024 slots x 16B
                    int cid = it*128 + tid;
                    int row = cid>>3, kc = cid&7;
                    int kcs = kc ^ (row&7);
                    gload16(Bbase + (size_t)(n0g+row)*Bstride + k0 + kcs*8,
                            lb + (size_t)(it*128 + wid*64)*8);
                }
            };

            f32x4 acc[4][4] = {};
            stage(0, kStart);
            __syncthreads();

            int nIter = (kEnd - kStart) >> 6;
            for (int i=0; i<nIter; ++i){
                int cur = i & 1;
                if (i+1 < nIter) stage(cur^1, kStart + ((i+1)<<6));
                ushort* la = As[cur];
                ushort* lb = Bs[cur];
                #pragma unroll
                for (int kk=0; kk<2; ++kk){
                    short8 af[4], bfr[4];
                    #pragma unroll
                    for (int mr=0;mr<4;++mr){
                        int r = mr*16 + (lane&15);
                        int j = (kk*4 + (lane>>4)) ^ (r&7);
                        af[mr] = *(const short8*)(la + r*64 + j*8);
                    }
                    #pragma unroll
                    for (int nr=0;nr<4;++nr){
                        int r = wid*64 + nr*16 + (lane&15);
                        int j = (kk*4 + (lane>>4)) ^ (r&7);
                        bfr[nr] = *(const short8*)(lb + r*64 + j*8);
                    }
                    #pragma unroll
                    for (int mr=0;mr<4;++mr)
                        #pragma unroll
                        for (int nr=0;nr<4;++nr)
                            acc[mr][nr] = __builtin_amdgcn_mfma_f32_16x16x32_bf16(af[mr], bfr[nr], acc[mr][nr], 0,0,0);
                }
                __syncthreads();
            }

            float* Pg = P + ((size_t)split*11 + g)*BH_;
            #pragma unroll
            for (int mr=0;mr<4;++mr){
                #pragma unroll
                for (int nr=0;nr<4;++nr){
                    int col = n0g + wid*64 + nr*16 + (lane&15);
                    #pragma unroll
                    for (int r=0;r<4;++r){
                        int rowg = m0 + mr*16 + (lane>>4)*4 + r;
                        astoref(&Pg[(size_t)rowg*H_ + col], acc[mr][nr][r]);
                    }
                }
            }
        }
        gbarrier(cnts, bid, (u32)(2*t+1));

        // ================= phase B: update (blocks 0..255) =================
        if (bid < B_){
            int b = bid;
            const float* Pb = P + (size_t)b*H_;
            int j0 = tid*8;                      // 8 consecutive elements/thread
            float lY[8], lI[8], lPv[8], lN[8], fv[8], ov[8];
            float v0=0,v1=0,v2=0,v3=0;

            float gg[11][8];
            #pragma unroll
            for (int gi=0; gi<11; ++gi){
                const float* p0 = Pb + (size_t)gi*BH_ + j0;
                const float* p1 = Pb + (size_t)(11+gi)*BH_ + j0;
                #pragma unroll
                for (int q=0;q<8;++q) gg[gi][q] = aloadf(p0+q) + aloadf(p1+q);
            }
            #pragma unroll
            for (int q=0;q<8;++q){
                int j = j0 + q;
                fv[q] = sigmf(gg[0][q] + bp.b[0][j]);
                ov[q] = sigmf(gg[1][q] + bp.b[1][j]);
                lY[q]  = tanhfast(gg[2][q] + bp.b[2][j]) * sigmf(gg[6][q] + bp.b[6][j]);
                lI[q]  = tanhfast(gg[3][q] + bp.b[3][j]) * sigmf(gg[7][q] + bp.b[7][j]);
                lPv[q] = tanhfast(gg[4][q] + bp.b[4][j]) * sigmf(gg[8][q] + bp.b[8][j]);
                lN[q]  = tanhfast(gg[5][q] + bp.b[5][j]) * sigmf(gg[9][q] + bp.b[9][j]);
                float gA = gg[10][q];
                v0 += lY[q]*gA; v1 += lI[q]*gA; v2 += lPv[q]*gA; v3 += lN[q]*gA;
            }
            #pragma unroll
            for (int d=32; d>=1; d>>=1){
                v0 += __shfl_down(v0,d); v1 += __shfl_down(v1,d);
                v2 += __shfl_down(v2,d); v3 += __shfl_down(v3,d);
            }
            float* red = (float*)&As[0][0];
            if (lane==0){ red[wid*4+0]=v0; red[wid*4+1]=v1; red[wid*4+2]=v2; red[wid*4+3]=v3; }
            __syncthreads();
            float sY = red[0]+red[4];
            float sI = red[1]+red[5];
            float sP = red[2]+red[6];
            float sN = red[3]+red[7];

            float zp = 0.f;
            #pragma unroll
            for (int q=0;q<8;++q){
                int j = j0 + q;
                zp += __expf(tanhfast(sY + bp.bA[0][j]));
                zp += __expf(tanhfast(sI + bp.bA[1][j]));
                zp += __expf(tanhfast(sP + bp.bA[2][j]));
                zp += __expf(tanhfast(sN + bp.bA[3][j]));
            }
            #pragma unroll
            for (int d=32; d>=1; d>>=1) zp += __shfl_down(zp,d);
            float* zred = red + 8;
            if (lane==0) zred[wid] = zp;
            __syncthreads();
            float Z = zred[0]+zred[1];
            float Zi = 1.0f / Z;
            float a0 = __expf(tanhfast(sY + bp.bA[0][0]))*Zi;
            float a1 = __expf(tanhfast(sY + bp.bA[0][1]))*Zi;
            float a2 = __expf(tanhfast(sY + bp.bA[0][2]))*Zi;
            float a3 = __expf(tanhfast(sY + bp.bA[0][3]))*Zi;

            ushort cb16[8], hb16[8];
            float ho[8];
            #pragma unroll
            for (int q=0;q<8;++q){
                float lT = a0*lY[q] + a1*lI[q] + a2*lPv[q] + a3*lN[q];
                float cn = creg[q]*fv[q] + lT;
                creg[q] = cn;
                cb16[q] = bf16bits(cn);
                float hn = tanhfast(cn)*ov[q];
                hb16[q] = bf16bits(hn);
                ho[q] = hn;
            }
            // coherent packed stores (read next step cross-XCD)
            u64* cb64 = (u64*)(cbuf + (size_t)b*H_ + j0);
            u64* hb64 = (u64*)(hb   + (size_t)b*H_ + j0);
            astore64(cb64,   *(u64*)&cb16[0]);
            astore64(cb64+1, *(u64*)&cb16[4]);
            astore64(hb64,   *(u64*)&hb16[0]);
            astore64(hb64+1, *(u64*)&hb16[4]);
            float4* o4 = (float4*)(out + ((size_t)b*T_ + t)*H_ + j0);
            o4[0] = *(float4*)&ho[0];
            o4[1] = *(float4*)&ho[4];
        }
        if (t < T_-1) gbarrier(cnts, bid, (u32)(2*t+2));
    }
}

extern "C" void kernel_launch(void* const* d_in, const int* in_sizes, int n_in,
                              void* d_out, int out_size, void* d_ws, size_t ws_size,
                              hipStream_t stream)
{
    WPtrs wp; BPtrs bp;
    for (int i=0;i<10;++i){ wp.W[i] = (const float*)d_in[2*i]; bp.b[i] = (const float*)d_in[2*i+1]; }
    wp.wA = (const float*)d_in[20];
    for (int i=0;i<4;++i) bp.bA[i] = (const float*)d_in[21+i];
    const float* xY = (const float*)d_in[25];
    const float* xI = (const float*)d_in[26];
    const float* xP = (const float*)d_in[27];
    const float* xN = (const float*)d_in[28];

    char* w = (char*)d_ws;
    size_t off = 0;
    ushort* Wt  = (ushort*)(w+off); off += (size_t)10*H_*C_*2;        // 31.46 MB
    ushort* wAt = (ushort*)(w+off); off += (size_t)H_*H_*2;           // 2 MB
    ushort* xb  = (ushort*)(w+off); off += (size_t)4*B_*T_*IN_*2;     // 134.2 MB
    float*  P   = (float*)(w+off);  off += (size_t)22*BH_*4;          // 23 MB
    ushort* hb  = (ushort*)(w+off); off += (size_t)BH_*2;             // 0.5 MB
    ushort* cbuf= (ushort*)(w+off); off += (size_t)BH_*2;             // 0.5 MB
    u32*    cnts= (u32*)(w+off);    off += 16*64*4;                   // 4 KB

    // zero hb, cbuf, barrier counters (contiguous)
    hipMemsetAsync(hb, 0, (size_t)4*BH_ + 16*64*4, stream);

    transpose_w<<<dim3(C_/32, H_/32, 11), dim3(32,8), 0, stream>>>(wp, Wt, wAt);
    convert_x<<<(4u*B_*T_*IN_/4)/256, 256, 0, stream>>>(xY,xI,xP,xN, xb);

    persist<<<NBLK, 128, 0, stream>>>(Wt, wAt, xb, hb, cbuf, P, bp, (float*)d_out, cnts);
}

// Round 8
// 12117.599 us; speedup vs baseline: 2.3148x; 1.0980x over previous
//
#include <hip/hip_runtime.h>
#include <hip/hip_bf16.h>

#define H_ 1024
#define C_ 1536
#define B_ 256
#define T_ 128
#define IN_ 512
#define BH_ (B_*H_)
#define NBLK 704

typedef __hip_bfloat16 bf16;
typedef __attribute__((ext_vector_type(8))) short short8;
typedef __attribute__((ext_vector_type(4))) float f32x4;
typedef unsigned int u32;
typedef unsigned long long u64;

struct WPtrs { const float* W[10]; const float* wA; };
struct BPtrs { const float* b[10]; const float* bA[4]; };

__device__ __forceinline__ float sigmf(float x){ return 1.0f/(1.0f + __expf(-x)); }
__device__ __forceinline__ float tanhfast(float x){ return 1.0f - 2.0f/(__expf(2.0f*x) + 1.0f); }

__device__ __forceinline__ ushort bf16bits(float f){
    bf16 b = __float2bfloat16(f);
    return *reinterpret_cast<ushort*>(&b);
}

// ---- coherent (cross-XCD) access helpers: relaxed agent-scope atomics.
// Proven correct on this HW in rounds 6/7.
__device__ __forceinline__ float aloadf(const float* p){
    return __hip_atomic_load(p, __ATOMIC_RELAXED, __HIP_MEMORY_SCOPE_AGENT);
}
__device__ __forceinline__ void astoref(float* p, float v){
    __hip_atomic_store(p, v, __ATOMIC_RELAXED, __HIP_MEMORY_SCOPE_AGENT);
}
__device__ __forceinline__ u64 aload64(const u64* p){
    return __hip_atomic_load(p, __ATOMIC_RELAXED, __HIP_MEMORY_SCOPE_AGENT);
}
__device__ __forceinline__ void astore64(u64* p, u64 v){
    __hip_atomic_store(p, v, __ATOMIC_RELAXED, __HIP_MEMORY_SCOPE_AGENT);
}

// async global->LDS, 16B per lane (cached path — read-only data: weights, x)
__device__ __forceinline__ void gload16(const void* g, void* l){
    __builtin_amdgcn_global_load_lds((const __attribute__((address_space(1))) u32*)g,
                                     (__attribute__((address_space(3))) u32*)l, 16, 0, 0);
}

// ---- weight transpose+convert: src fp32 [K][H] -> dst bf16 [H][K]
__global__ void transpose_w(WPtrs wp, ushort* __restrict__ Wt, ushort* __restrict__ wAt)
{
    int g = blockIdx.z;
    int K = (g==10) ? H_ : C_;
    int k0 = blockIdx.x*32, n0 = blockIdx.y*32;
    if (k0 >= K) return;
    const float* src = (g==10) ? wp.wA : wp.W[g];
    __shared__ float tile[32][33];
    int tx = threadIdx.x, ty = threadIdx.y;
    #pragma unroll
    for (int i=0;i<32;i+=8)
        tile[ty+i][tx] = src[(size_t)(k0+ty+i)*H_ + n0 + tx];
    __syncthreads();
    ushort* dst = (g==10) ? wAt : (Wt + (size_t)g*H_*C_);
    #pragma unroll
    for (int i=0;i<32;i+=8)
        dst[(size_t)(n0+ty+i)*K + k0 + tx] = bf16bits(tile[tx][ty+i]);
}

// ---- x fp32 -> bf16, all 4 factor arrays
__global__ void convert_x(const float* __restrict__ xY, const float* __restrict__ xI,
                          const float* __restrict__ xP, const float* __restrict__ xN,
                          ushort* __restrict__ xb)
{
    size_t idx = (size_t)blockIdx.x*blockDim.x + threadIdx.x;
    size_t base = idx*4;
    size_t a = base >> 24;
    size_t off = base & ((size_t)(1u<<24)-1);
    const float* s = (a==0)?xY:(a==1)?xI:(a==2)?xP:xN;
    float4 v = *(const float4*)(s + off);
    ushort4 o;
    o.x = bf16bits(v.x); o.y = bf16bits(v.y); o.z = bf16bits(v.z); o.w = bf16bits(v.w);
    *(ushort4*)(xb + base) = o;
}

// ---- grid barrier: 16 spread counters, monotonic phase targets.
// NO threadfence (would invalidate L2 and evict resident weights).
__device__ __forceinline__ void gbarrier(u32* cnts, int bid, u32 phase)
{
    asm volatile("s_waitcnt vmcnt(0)" ::: "memory");
    __syncthreads();
    if (threadIdx.x == 0){
        __hip_atomic_fetch_add(&cnts[(bid & 15) << 6], 1u,
                               __ATOMIC_RELAXED, __HIP_MEMORY_SCOPE_AGENT);
        u32 target = (u32)NBLK * phase;
        for (;;){
            u32 s = 0;
            #pragma unroll
            for (int i=0;i<16;++i)
                s += __hip_atomic_load(&cnts[i<<6], __ATOMIC_RELAXED, __HIP_MEMORY_SCOPE_AGENT);
            if (s >= target) break;
            __builtin_amdgcn_s_sleep(2);
        }
    }
    __syncthreads();
}

// ---- persistent kernel: whole T-loop. 704 blocks x 128 threads (2 waves).
// Phase A K-loop uses the T14 async-stage split:
//   iter i: issue A(i+1) coherent loads -> regs (or gload_lds for x-part),
//           issue B(i+1) gload_lds, MFMA on buf[i], ds_write A(i+1), barrier.
__global__ __launch_bounds__(128, 2) void persist(
    const ushort* __restrict__ Wt, const ushort* __restrict__ wAt,
    const ushort* __restrict__ xb, ushort* __restrict__ hb,
    ushort* __restrict__ cbuf, float* __restrict__ P,
    BPtrs bp, float* __restrict__ out, u32* __restrict__ cnts)
{
    int bid = blockIdx.x;
    int xcd = bid & 7, lid = bid >> 3;     // lid in [0,88)
    int ntile = xcd*11 + (lid >> 3);       // [0,88)
    int rem = lid & 7;
    int mtile = rem >> 1;                  // [0,4)
    int split = rem & 1;                   // [0,2)
    int nglob0 = ntile*128;
    int g = nglob0 >> 10;
    int n0g = nglob0 & 1023;
    int m0 = mtile*64;
    bool isA = (g==10);
    const ushort* Bbase = isA ? wAt : (Wt + (size_t)g*H_*C_);
    size_t Bstride = isA ? 1024 : 1536;
    int kStart = isA ? split*512 : split*768;
    int kEnd   = isA ? kStart+512 : kStart+768;
    int xs = (g==3)?1:(g==4)?2:(g==5)?3:0;
    const ushort* xsrc = xb + (size_t)xs*((size_t)B_*T_*IN_);
    const ushort* Ah = isA ? cbuf : hb;

    __shared__ ushort As[2][64*64];
    __shared__ ushort Bs[2][128*64];
    int tid = threadIdx.x;
    int wid = tid>>6, lane = tid&63;

    // cell state for update phase (block bid<256 owns row bid forever)
    float creg[8];
    #pragma unroll
    for (int q=0;q<8;++q) creg[q] = 0.f;

    ulong2 rA[4];   // in-flight A slots (h-part iters)

    for (int t=0; t<T_; ++t){
        // ================= phase A: GEMM =================
        {
            // issue loads for K-tile k0 into rA (h) or LDS buf (x), plus B gloads
            auto stage_issue = [&](int buf, int k0){
                ushort* la = As[buf];
                if (isA || k0 < 1024){
                    #pragma unroll
                    for (int it=0; it<4; ++it){
                        int cid = it*128 + tid;
                        int row = cid>>3, kc = cid&7;
                        const u64* s64 = (const u64*)(Ah + (size_t)(m0+row)*H_ + k0 + kc*8);
                        rA[it].x = aload64(s64);
                        rA[it].y = aload64(s64+1);
                    }
                } else {
                    #pragma unroll
                    for (int it=0; it<4; ++it){
                        int cid = it*128 + tid;
                        int row = cid>>3, kc = cid&7;
                        int kcs = kc ^ (row&7);
                        gload16(xsrc + ((size_t)(m0+row)*T_ + t)*IN_ + (k0 + kcs*8 - 1024),
                                la + (size_t)(it*128 + wid*64)*8);
                    }
                }
                ushort* lb = Bs[buf];
                #pragma unroll
                for (int it=0; it<8; ++it){
                    int cid = it*128 + tid;
                    int row = cid>>3, kc = cid&7;
                    int kcs = kc ^ (row&7);
                    gload16(Bbase + (size_t)(n0g+row)*Bstride + k0 + kcs*8,
                            lb + (size_t)(it*128 + wid*64)*8);
                }
            };
            // complete the h-part staging: swizzled ds_write of rA
            auto stage_finish = [&](int buf, int k0){
                if (isA || k0 < 1024){
                    ushort* la = As[buf];
                    #pragma unroll
                    for (int it=0; it<4; ++it){
                        int cid = it*128 + tid;
                        int row = cid>>3, kc = cid&7;
                        int kcs = kc ^ (row&7);
                        *(ulong2*)(la + (size_t)row*64 + kcs*8) = rA[it];
                    }
                }
            };

            f32x4 acc[4][4] = {};
            stage_issue(0, kStart);
            stage_finish(0, kStart);
            __syncthreads();

            int nIter = (kEnd - kStart) >> 6;
            int cur = 0;
            for (int i=0; i<nIter; ++i){
                int k0n = kStart + ((i+1)<<6);
                if (i+1 < nIter) stage_issue(cur^1, k0n);

                ushort* la = As[cur];
                ushort* lb = Bs[cur];
                #pragma unroll
                for (int kk=0; kk<2; ++kk){
                    short8 af[4], bfr[4];
                    #pragma unroll
                    for (int mr=0;mr<4;++mr){
                        int r = mr*16 + (lane&15);
                        int j = (kk*4 + (lane>>4)) ^ (r&7);
                        af[mr] = *(const short8*)(la + r*64 + j*8);
                    }
                    #pragma unroll
                    for (int nr=0;nr<4;++nr){
                        int r = wid*64 + nr*16 + (lane&15);
                        int j = (kk*4 + (lane>>4)) ^ (r&7);
                        bfr[nr] = *(const short8*)(lb + r*64 + j*8);
                    }
                    #pragma unroll
                    for (int mr=0;mr<4;++mr)
                        #pragma unroll
                        for (int nr=0;nr<4;++nr)
                            acc[mr][nr] = __builtin_amdgcn_mfma_f32_16x16x32_bf16(af[mr], bfr[nr], acc[mr][nr], 0,0,0);
                }

                if (i+1 < nIter) stage_finish(cur^1, k0n);
                __syncthreads();
                cur ^= 1;
            }

            float* Pg = P + ((size_t)split*11 + g)*BH_;
            #pragma unroll
            for (int mr=0;mr<4;++mr){
                #pragma unroll
                for (int nr=0;nr<4;++nr){
                    int col = n0g + wid*64 + nr*16 + (lane&15);
                    #pragma unroll
                    for (int r=0;r<4;++r){
                        int rowg = m0 + mr*16 + (lane>>4)*4 + r;
                        astoref(&Pg[(size_t)rowg*H_ + col], acc[mr][nr][r]);
                    }
                }
            }
        }
        gbarrier(cnts, bid, (u32)(2*t+1));

        // ================= phase B: update (blocks 0..255) =================
        if (bid < B_){
            int b = bid;
            const float* Pb = P + (size_t)b*H_;
            int j0 = tid*8;                      // 8 consecutive elements/thread
            float lY[8], lI[8], lPv[8], lN[8], fv[8], ov[8];
            float v0=0,v1=0,v2=0,v3=0;

            float gg[11][8];
            #pragma unroll
            for (int gi=0; gi<11; ++gi){
                const float* p0 = Pb + (size_t)gi*BH_ + j0;
                const float* p1 = Pb + (size_t)(11+gi)*BH_ + j0;
                #pragma unroll
                for (int q=0;q<8;++q) gg[gi][q] = aloadf(p0+q) + aloadf(p1+q);
            }
            #pragma unroll
            for (int q=0;q<8;++q){
                int j = j0 + q;
                fv[q] = sigmf(gg[0][q] + bp.b[0][j]);
                ov[q] = sigmf(gg[1][q] + bp.b[1][j]);
                lY[q]  = tanhfast(gg[2][q] + bp.b[2][j]) * sigmf(gg[6][q] + bp.b[6][j]);
                lI[q]  = tanhfast(gg[3][q] + bp.b[3][j]) * sigmf(gg[7][q] + bp.b[7][j]);
                lPv[q] = tanhfast(gg[4][q] + bp.b[4][j]) * sigmf(gg[8][q] + bp.b[8][j]);
                lN[q]  = tanhfast(gg[5][q] + bp.b[5][j]) * sigmf(gg[9][q] + bp.b[9][j]);
                float gA = gg[10][q];
                v0 += lY[q]*gA; v1 += lI[q]*gA; v2 += lPv[q]*gA; v3 += lN[q]*gA;
            }
            #pragma unroll
            for (int d=32; d>=1; d>>=1){
                v0 += __shfl_down(v0,d); v1 += __shfl_down(v1,d);
                v2 += __shfl_down(v2,d); v3 += __shfl_down(v3,d);
            }
            float* red = (float*)&As[0][0];
            if (lane==0){ red[wid*4+0]=v0; red[wid*4+1]=v1; red[wid*4+2]=v2; red[wid*4+3]=v3; }
            __syncthreads();
            float sY = red[0]+red[4];
            float sI = red[1]+red[5];
            float sP = red[2]+red[6];
            float sN = red[3]+red[7];

            float zp = 0.f;
            #pragma unroll
            for (int q=0;q<8;++q){
                int j = j0 + q;
                zp += __expf(tanhfast(sY + bp.bA[0][j]));
                zp += __expf(tanhfast(sI + bp.bA[1][j]));
                zp += __expf(tanhfast(sP + bp.bA[2][j]));
                zp += __expf(tanhfast(sN + bp.bA[3][j]));
            }
            #pragma unroll
            for (int d=32; d>=1; d>>=1) zp += __shfl_down(zp,d);
            float* zred = red + 8;
            if (lane==0) zred[wid] = zp;
            __syncthreads();
            float Z = zred[0]+zred[1];
            float Zi = 1.0f / Z;
            float a0 = __expf(tanhfast(sY + bp.bA[0][0]))*Zi;
            float a1 = __expf(tanhfast(sY + bp.bA[0][1]))*Zi;
            float a2 = __expf(tanhfast(sY + bp.bA[0][2]))*Zi;
            float a3 = __expf(tanhfast(sY + bp.bA[0][3]))*Zi;

            ushort cb16[8], hb16[8];
            float ho[8];
            #pragma unroll
            for (int q=0;q<8;++q){
                float lT = a0*lY[q] + a1*lI[q] + a2*lPv[q] + a3*lN[q];
                float cn = creg[q]*fv[q] + lT;
                creg[q] = cn;
                cb16[q] = bf16bits(cn);
                float hn = tanhfast(cn)*ov[q];
                hb16[q] = bf16bits(hn);
                ho[q] = hn;
            }
            u64* cb64 = (u64*)(cbuf + (size_t)b*H_ + j0);
            u64* hb64 = (u64*)(hb   + (size_t)b*H_ + j0);
            astore64(cb64,   *(u64*)&cb16[0]);
            astore64(cb64+1, *(u64*)&cb16[4]);
            astore64(hb64,   *(u64*)&hb16[0]);
            astore64(hb64+1, *(u64*)&hb16[4]);
            float4* o4 = (float4*)(out + ((size_t)b*T_ + t)*H_ + j0);
            o4[0] = *(float4*)&ho[0];
            o4[1] = *(float4*)&ho[4];
        }
        if (t < T_-1) gbarrier(cnts, bid, (u32)(2*t+2));
    }
}

extern "C" void kernel_launch(void* const* d_in, const int* in_sizes, int n_in,
                              void* d_out, int out_size, void* d_ws, size_t ws_size,
                              hipStream_t stream)
{
    WPtrs wp; BPtrs bp;
    for (int i=0;i<10;++i){ wp.W[i] = (const float*)d_in[2*i]; bp.b[i] = (const float*)d_in[2*i+1]; }
    wp.wA = (const float*)d_in[20];
    for (int i=0;i<4;++i) bp.bA[i] = (const float*)d_in[21+i];
    const float* xY = (const float*)d_in[25];
    const float* xI = (const float*)d_in[26];
    const float* xP = (const float*)d_in[27];
    const float* xN = (const float*)d_in[28];

    char* w = (char*)d_ws;
    size_t off = 0;
    ushort* Wt  = (ushort*)(w+off); off += (size_t)10*H_*C_*2;        // 31.46 MB
    ushort* wAt = (ushort*)(w+off); off += (size_t)H_*H_*2;           // 2 MB
    ushort* xb  = (ushort*)(w+off); off += (size_t)4*B_*T_*IN_*2;     // 134.2 MB
    float*  P   = (float*)(w+off);  off += (size_t)22*BH_*4;          // 23 MB
    ushort* hb  = (ushort*)(w+off); off += (size_t)BH_*2;             // 0.5 MB
    ushort* cbuf= (ushort*)(w+off); off += (size_t)BH_*2;             // 0.5 MB
    u32*    cnts= (u32*)(w+off);    off += 16*64*4;                   // 4 KB

    // zero hb, cbuf, barrier counters (contiguous)
    hipMemsetAsync(hb, 0, (size_t)4*BH_ + 16*64*4, stream);

    transpose_w<<<dim3(C_/32, H_/32, 11), dim3(32,8), 0, stream>>>(wp, Wt, wAt);
    convert_x<<<(4u*B_*T_*IN_/4)/256, 256, 0, stream>>>(xY,xI,xP,xN, xb);

    persist<<<NBLK, 128, 0, stream>>>(Wt, wAt, xb, hb, cbuf, P, bp, (float*)d_out, cnts);
}

// Round 9
// 10106.057 us; speedup vs baseline: 2.7756x; 1.1990x over previous
//
#include <hip/hip_runtime.h>
#include <hip/hip_bf16.h>

#define H_ 1024
#define C_ 1536
#define B_ 256
#define T_ 128
#define IN_ 512
#define BH_ (B_*H_)
#define NBLK 704
#define RMASK 63   // 64-slot h/c ring

typedef __hip_bfloat16 bf16;
typedef __attribute__((ext_vector_type(8))) short short8;
typedef __attribute__((ext_vector_type(4))) float f32x4;
typedef unsigned int u32;
typedef unsigned long long u64;

struct WPtrs { const float* W[10]; const float* wA; };
struct BPtrs { const float* b[10]; const float* bA[4]; };

__device__ __forceinline__ float sigmf(float x){ return 1.0f/(1.0f + __expf(-x)); }
__device__ __forceinline__ float tanhfast(float x){ return 1.0f - 2.0f/(__expf(2.0f*x) + 1.0f); }

__device__ __forceinline__ ushort bf16bits(float f){
    bf16 b = __float2bfloat16(f);
    return *reinterpret_cast<ushort*>(&b);
}

// coherent (cross-XCD) helpers — proven r6-r8
__device__ __forceinline__ float aloadf(const float* p){
    return __hip_atomic_load(p, __ATOMIC_RELAXED, __HIP_MEMORY_SCOPE_AGENT);
}
__device__ __forceinline__ void astoref(float* p, float v){
    __hip_atomic_store(p, v, __ATOMIC_RELAXED, __HIP_MEMORY_SCOPE_AGENT);
}
__device__ __forceinline__ u64 aload64(const u64* p){
    return __hip_atomic_load(p, __ATOMIC_RELAXED, __HIP_MEMORY_SCOPE_AGENT);
}
__device__ __forceinline__ void astore64(u64* p, u64 v){
    __hip_atomic_store(p, v, __ATOMIC_RELAXED, __HIP_MEMORY_SCOPE_AGENT);
}

// async global->LDS, 16B/lane, plain cached path (weights, ring, x)
__device__ __forceinline__ void gload16(const void* g, void* l){
    __builtin_amdgcn_global_load_lds((const __attribute__((address_space(1))) u32*)g,
                                     (__attribute__((address_space(3))) u32*)l, 16, 0, 0);
}

// ---- weight transpose+convert: src fp32 [K][H] -> dst bf16 [H][K]
__global__ void transpose_w(WPtrs wp, ushort* __restrict__ Wt, ushort* __restrict__ wAt)
{
    int g = blockIdx.z;
    int K = (g==10) ? H_ : C_;
    int k0 = blockIdx.x*32, n0 = blockIdx.y*32;
    if (k0 >= K) return;
    const float* src = (g==10) ? wp.wA : wp.W[g];
    __shared__ float tile[32][33];
    int tx = threadIdx.x, ty = threadIdx.y;
    #pragma unroll
    for (int i=0;i<32;i+=8)
        tile[ty+i][tx] = src[(size_t)(k0+ty+i)*H_ + n0 + tx];
    __syncthreads();
    ushort* dst = (g==10) ? wAt : (Wt + (size_t)g*H_*C_);
    #pragma unroll
    for (int i=0;i<32;i+=8)
        dst[(size_t)(n0+ty+i)*K + k0 + tx] = bf16bits(tile[tx][ty+i]);
}

// ---- persistent kernel: whole T-loop. 704 blocks x 128 threads (2 waves).
// Geometry: 8 XCD x 11 ntile(128) x 4 mtile(64) x 2 ksplit (r5-proven).
// h/c flow through a 64-slot ring: updaters write coherent (MALL), gemm reads
// plain cached gload16 (first-touch lines -> fresh MALL fill, L2 dedup).
__global__ __launch_bounds__(128, 2) void persist(
    const ushort* __restrict__ Wt, const ushort* __restrict__ wAt,
    const float* __restrict__ xY, const float* __restrict__ xI,
    const float* __restrict__ xPf, const float* __restrict__ xNf,
    ushort* __restrict__ ring, float* __restrict__ P,
    BPtrs bp, float* __restrict__ out, u32* __restrict__ cnts)
{
    int bid = blockIdx.x;
    int xcd = bid & 7, lid = bid >> 3;     // lid in [0,88)
    int ntile = xcd*11 + (lid >> 3);       // [0,88)
    int rem = lid & 7;
    int mtile = rem >> 1;                  // [0,4)
    int split = rem & 1;                   // [0,2)
    int g = ntile >> 3;                    // 8 tiles of 128 per gate
    int n0g = (ntile & 7)*128;
    int m0 = mtile*64;
    bool isA = (g==10);
    const ushort* Bbase = isA ? wAt : (Wt + (size_t)g*H_*C_);
    size_t Bstride = isA ? 1024 : 1536;
    int kStart = isA ? split*512 : split*768;
    int nIter  = isA ? 8 : 12;
    const float* xf = (g==3)?xI:(g==4)?xPf:(g==5)?xNf:xY;

    __shared__ ushort As[2][64*64];
    __shared__ ushort Bs[2][128*64];
    int tid = threadIdx.x;
    int wid = tid>>6, lane = tid&63;

    float creg[8];
    #pragma unroll
    for (int q=0;q<8;++q) creg[q] = 0.f;

    float xr0[8], xr1[8], xr2[8], xr3[8];   // x staging regs (static idx)

    for (int t=0; t<T_; ++t){
        const ushort* hc = ring + (size_t)(t & RMASK)*2*BH_ + (isA ? BH_ : 0);

        // ---- staging helpers for this t ----
        auto stageB = [&](int buf, int k0){
            ushort* lb = Bs[buf];
            #pragma unroll
            for (int it=0; it<8; ++it){
                int cid = it*128 + tid;
                int row = cid>>3, kc = cid&7;
                int kcs = kc ^ (row&7);
                gload16(Bbase + (size_t)(n0g+row)*Bstride + k0 + kcs*8,
                        lb + (size_t)(it*128 + wid*64)*8);
            }
        };
        auto stageA_h = [&](int buf, int k0){   // k0+63 < 1024 guaranteed by caller
            ushort* la = As[buf];
            #pragma unroll
            for (int it=0; it<4; ++it){
                int cid = it*128 + tid;
                int row = cid>>3, kc = cid&7;
                int kcs = kc ^ (row&7);
                gload16(hc + (size_t)(m0+row)*H_ + k0 + kcs*8,
                        la + (size_t)(it*128 + wid*64)*8);
            }
        };
        auto stageX_issue = [&](int k0){        // k0 >= 1024: x from fp32 input
            #pragma unroll
            for (int it=0; it<4; ++it){
                int cid = it*128 + tid;
                int row = cid>>3, kc = cid&7;
                const float4* s4 = (const float4*)(xf + ((size_t)(m0+row)*T_ + t)*IN_ + (k0 + kc*8 - 1024));
                float4 a = s4[0], b = s4[1];
                float* xr = (it==0)?xr0:(it==1)?xr1:(it==2)?xr2:xr3;
                xr[0]=a.x; xr[1]=a.y; xr[2]=a.z; xr[3]=a.w;
                xr[4]=b.x; xr[5]=b.y; xr[6]=b.z; xr[7]=b.w;
            }
        };
        auto stageX_finish = [&](int buf){
            ushort* la = As[buf];
            #pragma unroll
            for (int it=0; it<4; ++it){
                int cid = it*128 + tid;
                int row = cid>>3, kc = cid&7;
                int kcs = kc ^ (row&7);
                const float* xr = (it==0)?xr0:(it==1)?xr1:(it==2)?xr2:xr3;
                ushort t8[8];
                #pragma unroll
                for (int q=0;q<8;++q) t8[q] = bf16bits(xr[q]);
                *(ulong2*)(la + (size_t)row*64 + kcs*8) = *(ulong2*)t8;
            }
        };

        // ================= phase A: GEMM =================
        {
            if (t == 0) stageB(0, kStart);       // t>0: prefetched at GB1
            stageA_h(0, kStart);                 // kStart in {0,512,768} < 1024
            __syncthreads();                     // buf0 ready

            f32x4 acc[4][4] = {};
            int cur = 0;
            for (int i=0; i<nIter; ++i){
                int k0n = kStart + ((i+1)<<6);
                bool more = (i+1 < nIter);
                bool nx_x = false;
                if (more){
                    nx_x = (!isA) && (k0n >= 1024);
                    if (nx_x) stageX_issue(k0n);
                    else      stageA_h(cur^1, k0n);
                    stageB(cur^1, k0n);
                }
                ushort* la = As[cur];
                ushort* lb = Bs[cur];
                #pragma unroll
                for (int kk=0; kk<2; ++kk){
                    short8 af[4], bfr[4];
                    #pragma unroll
                    for (int mr=0;mr<4;++mr){
                        int r = mr*16 + (lane&15);
                        int j = (kk*4 + (lane>>4)) ^ (r&7);
                        af[mr] = *(const short8*)(la + r*64 + j*8);
                    }
                    #pragma unroll
                    for (int nr=0;nr<4;++nr){
                        int r = wid*64 + nr*16 + (lane&15);
                        int j = (kk*4 + (lane>>4)) ^ (r&7);
                        bfr[nr] = *(const short8*)(lb + r*64 + j*8);
                    }
                    #pragma unroll
                    for (int mr=0;mr<4;++mr)
                        #pragma unroll
                        for (int nr=0;nr<4;++nr)
                            acc[mr][nr] = __builtin_amdgcn_mfma_f32_16x16x32_bf16(af[mr], bfr[nr], acc[mr][nr], 0,0,0);
                }
                if (more && nx_x) stageX_finish(cur^1);
                __syncthreads();
                cur ^= 1;
            }

            float* Pg = P + ((size_t)split*11 + g)*BH_;
            #pragma unroll
            for (int mr=0;mr<4;++mr){
                #pragma unroll
                for (int nr=0;nr<4;++nr){
                    int col = n0g + wid*64 + nr*16 + (lane&15);
                    #pragma unroll
                    for (int r=0;r<4;++r){
                        int rowg = m0 + mr*16 + (lane>>4)*4 + r;
                        astoref(&Pg[(size_t)rowg*H_ + col], acc[mr][nr][r]);
                    }
                }
            }
        }

        // ---- GB1: drain P stores, then overlap next-step B prefetch ----
        asm volatile("s_waitcnt vmcnt(0)" ::: "memory");   // P stores at MALL
        if (t+1 < T_) stageB(0, kStart);                   // prefetch B(t+1), stays in flight
        __builtin_amdgcn_s_barrier();
        if (tid == 0){
            __hip_atomic_fetch_add(&cnts[(bid & 15) << 6], 1u,
                                   __ATOMIC_RELAXED, __HIP_MEMORY_SCOPE_AGENT);
            u32 target = (u32)NBLK * (u32)(2*t+1);
            for (;;){
                u32 s = 0;
                #pragma unroll
                for (int i=0;i<16;++i)
                    s += __hip_atomic_load(&cnts[i<<6], __ATOMIC_RELAXED, __HIP_MEMORY_SCOPE_AGENT);
                if (s >= target) break;
                __builtin_amdgcn_s_sleep(2);
            }
        }
        __builtin_amdgcn_s_barrier();

        // ================= phase B: update (blocks 0..255) =================
        if (bid < B_){
            int b = bid;
            const float* Pb = P + (size_t)b*H_;
            int j0 = tid*8;
            float lY[8], lI[8], lPv[8], lN[8], fv[8], ov[8];
            float v0=0,v1=0,v2=0,v3=0;

            float gg[11][8];
            #pragma unroll
            for (int gi=0; gi<11; ++gi){
                const u64* p0 = (const u64*)(Pb + (size_t)gi*BH_ + j0);
                const u64* p1 = (const u64*)(Pb + (size_t)(11+gi)*BH_ + j0);
                #pragma unroll
                for (int q=0;q<4;++q){
                    u64 a = aload64(p0+q), c = aload64(p1+q);
                    float2 fa, fc;
                    __builtin_memcpy(&fa, &a, 8);
                    __builtin_memcpy(&fc, &c, 8);
                    gg[gi][2*q]   = fa.x + fc.x;
                    gg[gi][2*q+1] = fa.y + fc.y;
                }
            }
            #pragma unroll
            for (int q=0;q<8;++q){
                int j = j0 + q;
                fv[q] = sigmf(gg[0][q] + bp.b[0][j]);
                ov[q] = sigmf(gg[1][q] + bp.b[1][j]);
                lY[q]  = tanhfast(gg[2][q] + bp.b[2][j]) * sigmf(gg[6][q] + bp.b[6][j]);
                lI[q]  = tanhfast(gg[3][q] + bp.b[3][j]) * sigmf(gg[7][q] + bp.b[7][j]);
                lPv[q] = tanhfast(gg[4][q] + bp.b[4][j]) * sigmf(gg[8][q] + bp.b[8][j]);
                lN[q]  = tanhfast(gg[5][q] + bp.b[5][j]) * sigmf(gg[9][q] + bp.b[9][j]);
                float gA = gg[10][q];
                v0 += lY[q]*gA; v1 += lI[q]*gA; v2 += lPv[q]*gA; v3 += lN[q]*gA;
            }
            #pragma unroll
            for (int d=32; d>=1; d>>=1){
                v0 += __shfl_down(v0,d); v1 += __shfl_down(v1,d);
                v2 += __shfl_down(v2,d); v3 += __shfl_down(v3,d);
            }
            float* red = (float*)&As[0][0];
            if (lane==0){ red[wid*4+0]=v0; red[wid*4+1]=v1; red[wid*4+2]=v2; red[wid*4+3]=v3; }
            __syncthreads();
            float sY = red[0]+red[4];
            float sI = red[1]+red[5];
            float sP = red[2]+red[6];
            float sN = red[3]+red[7];

            float zp = 0.f;
            #pragma unroll
            for (int q=0;q<8;++q){
                int j = j0 + q;
                zp += __expf(tanhfast(sY + bp.bA[0][j]));
                zp += __expf(tanhfast(sI + bp.bA[1][j]));
                zp += __expf(tanhfast(sP + bp.bA[2][j]));
                zp += __expf(tanhfast(sN + bp.bA[3][j]));
            }
            #pragma unroll
            for (int d=32; d>=1; d>>=1) zp += __shfl_down(zp,d);
            float* zred = red + 8;
            if (lane==0) zred[wid] = zp;
            __syncthreads();
            float Z = zred[0]+zred[1];
            float Zi = 1.0f / Z;
            float a0 = __expf(tanhfast(sY + bp.bA[0][0]))*Zi;
            float a1 = __expf(tanhfast(sY + bp.bA[0][1]))*Zi;
            float a2 = __expf(tanhfast(sY + bp.bA[0][2]))*Zi;
            float a3 = __expf(tanhfast(sY + bp.bA[0][3]))*Zi;

            ushort cb16[8], hb16[8];
            float ho[8];
            #pragma unroll
            for (int q=0;q<8;++q){
                float lT = a0*lY[q] + a1*lI[q] + a2*lPv[q] + a3*lN[q];
                float cn = creg[q]*fv[q] + lT;
                creg[q] = cn;
                cb16[q] = bf16bits(cn);
                float hn = tanhfast(cn)*ov[q];
                hb16[q] = bf16bits(hn);
                ho[q] = hn;
            }
            // coherent ring write: slot (t+1) — h plane 0, c plane 1
            ushort* rw = ring + (size_t)((t+1) & RMASK)*2*BH_ + (size_t)b*H_ + j0;
            astore64((u64*)rw,            *(u64*)&hb16[0]);
            astore64((u64*)rw + 1,        *(u64*)&hb16[4]);
            astore64((u64*)(rw + BH_),    *(u64*)&cb16[0]);
            astore64((u64*)(rw + BH_) + 1,*(u64*)&cb16[4]);
            float4* o4 = (float4*)(out + ((size_t)b*T_ + t)*H_ + j0);
            o4[0] = *(float4*)&ho[0];
            o4[1] = *(float4*)&ho[4];
        }

        // ---- GB2: drain ring writes, release next step ----
        if (t+1 < T_){
            asm volatile("s_waitcnt vmcnt(0)" ::: "memory");
            __syncthreads();
            if (tid == 0){
                __hip_atomic_fetch_add(&cnts[(bid & 15) << 6], 1u,
                                       __ATOMIC_RELAXED, __HIP_MEMORY_SCOPE_AGENT);
                u32 target = (u32)NBLK * (u32)(2*t+2);
                for (;;){
                    u32 s = 0;
                    #pragma unroll
                    for (int i=0;i<16;++i)
                        s += __hip_atomic_load(&cnts[i<<6], __ATOMIC_RELAXED, __HIP_MEMORY_SCOPE_AGENT);
                    if (s >= target) break;
                    __builtin_amdgcn_s_sleep(2);
                }
            }
            __syncthreads();
        }
    }
}

extern "C" void kernel_launch(void* const* d_in, const int* in_sizes, int n_in,
                              void* d_out, int out_size, void* d_ws, size_t ws_size,
                              hipStream_t stream)
{
    WPtrs wp; BPtrs bp;
    for (int i=0;i<10;++i){ wp.W[i] = (const float*)d_in[2*i]; bp.b[i] = (const float*)d_in[2*i+1]; }
    wp.wA = (const float*)d_in[20];
    for (int i=0;i<4;++i) bp.bA[i] = (const float*)d_in[21+i];
    const float* xY = (const float*)d_in[25];
    const float* xI = (const float*)d_in[26];
    const float* xP = (const float*)d_in[27];
    const float* xN = (const float*)d_in[28];

    char* w = (char*)d_ws;
    size_t off = 0;
    ushort* Wt  = (ushort*)(w+off); off += (size_t)10*H_*C_*2;        // 31.46 MB
    ushort* wAt = (ushort*)(w+off); off += (size_t)H_*H_*2;           // 2.10 MB
    float*  P   = (float*)(w+off);  off += (size_t)22*BH_*4;          // 23.07 MB
    u32*    cnts= (u32*)(w+off);    off += 4096;                      // 4 KB
    ushort* ring= (ushort*)(w+off); off += (size_t)(RMASK+1)*2*BH_*2; // 67.11 MB
    // total ~123.7 MB << proven ws floor (~191 MB)

    // zero barrier counters + ring slot 0 (h=c=0 initial state) — contiguous
    hipMemsetAsync(cnts, 0, 4096 + (size_t)2*BH_*2, stream);

    transpose_w<<<dim3(C_/32, H_/32, 11), dim3(32,8), 0, stream>>>(wp, Wt, wAt);

    persist<<<NBLK, 128, 0, stream>>>(Wt, wAt, xY, xI, xP, xN,
                                      ring, P, bp, (float*)d_out, cnts);
}

// Round 10
// 3690.671 us; speedup vs baseline: 7.6003x; 2.7383x over previous
//
#include <hip/hip_runtime.h>
#include <hip/hip_bf16.h>

#define H_ 1024
#define C_ 1536
#define B_ 256
#define T_ 128
#define IN_ 512
#define BH_ (B_*H_)

typedef __hip_bfloat16 bf16;
typedef __attribute__((ext_vector_type(8))) short short8;
typedef __attribute__((ext_vector_type(4))) float f32x4;
typedef unsigned int u32;

struct WPtrs { const float* W[10]; const float* wA; };
struct BPtrs { const float* b[10]; const float* bA[4]; };

__device__ __forceinline__ float sigmf(float x){ return 1.0f/(1.0f + __expf(-x)); }
__device__ __forceinline__ float tanhfast(float x){ return 1.0f - 2.0f/(__expf(2.0f*x) + 1.0f); }

__device__ __forceinline__ ushort bf16bits(float f){
    bf16 b = __float2bfloat16(f);
    return *reinterpret_cast<ushort*>(&b);
}

// async global->LDS, 16B per lane
__device__ __forceinline__ void gload16(const void* g, void* l){
    __builtin_amdgcn_global_load_lds((const __attribute__((address_space(1))) u32*)g,
                                     (__attribute__((address_space(3))) u32*)l, 16, 0, 0);
}

// ---- weight transpose+convert: src fp32 [K][H] -> dst bf16 [H][K]
__global__ void transpose_w(WPtrs wp, ushort* __restrict__ Wt, ushort* __restrict__ wAt)
{
    int g = blockIdx.z;
    int K = (g==10) ? H_ : C_;
    int k0 = blockIdx.x*32, n0 = blockIdx.y*32;
    if (k0 >= K) return;
    const float* src = (g==10) ? wp.wA : wp.W[g];
    __shared__ float tile[32][33];
    int tx = threadIdx.x, ty = threadIdx.y;
    #pragma unroll
    for (int i=0;i<32;i+=8)
        tile[ty+i][tx] = src[(size_t)(k0+ty+i)*H_ + n0 + tx];
    __syncthreads();
    ushort* dst = (g==10) ? wAt : (Wt + (size_t)g*H_*C_);
    #pragma unroll
    for (int i=0;i<32;i+=8)
        dst[(size_t)(n0+ty+i)*K + k0 + tx] = bf16bits(tile[tx][ty+i]);
}

// ---- per-step GEMM, split-K=2 (r5-proven geometry).
// 704 blocks = 8 XCD x 11 ntile(128) x 4 mtile(64) x 2 ksplit; 128 thr (2 waves),
// wave tile 64x64 (acc[4][4]); dbuf LDS 48KB, 1 barrier/K-iter.
// x-part staged directly from fp32 input via reg path (issue early, write late).
__global__ __launch_bounds__(128, 2) void gemm_step(
    const ushort* __restrict__ Wt, const ushort* __restrict__ wAt,
    const float* __restrict__ xY, const float* __restrict__ xI,
    const float* __restrict__ xPf, const float* __restrict__ xNf,
    const ushort* __restrict__ hb, const ushort* __restrict__ cbuf,
    float* __restrict__ P, int t)
{
    int bid = blockIdx.x;
    int xcd = bid & 7, lid = bid >> 3;     // [0,88)
    int ntile = xcd*11 + (lid >> 3);       // [0,88)
    int rem = lid & 7;
    int mtile = rem >> 1;                  // [0,4)
    int split = rem & 1;                   // [0,2)
    int g = ntile >> 3;
    int n0g = (ntile & 7)*128;
    int m0 = mtile*64;
    bool isA = (g==10);
    const ushort* Bbase = isA ? wAt : (Wt + (size_t)g*H_*C_);
    size_t Bstride = isA ? 1024 : 1536;
    int kStart = isA ? split*512 : split*768;
    int nIter  = isA ? 8 : 12;
    const float* xf = (g==3)?xI:(g==4)?xPf:(g==5)?xNf:xY;
    const ushort* Ah = isA ? cbuf : hb;

    __shared__ ushort As[2][64*64];
    __shared__ ushort Bs[2][128*64];
    int tid = threadIdx.x;
    int wid = tid>>6, lane = tid&63;

    float xr0[8], xr1[8], xr2[8], xr3[8];

    auto stageB = [&](int buf, int k0){
        ushort* lb = Bs[buf];
        #pragma unroll
        for (int it=0; it<8; ++it){
            int cid = it*128 + tid;
            int row = cid>>3, kc = cid&7;
            int kcs = kc ^ (row&7);
            gload16(Bbase + (size_t)(n0g+row)*Bstride + k0 + kcs*8,
                    lb + (size_t)(it*128 + wid*64)*8);
        }
    };
    auto stageA_h = [&](int buf, int k0){   // k0 tile fully < 1024
        ushort* la = As[buf];
        #pragma unroll
        for (int it=0; it<4; ++it){
            int cid = it*128 + tid;
            int row = cid>>3, kc = cid&7;
            int kcs = kc ^ (row&7);
            gload16(Ah + (size_t)(m0+row)*H_ + k0 + kcs*8,
                    la + (size_t)(it*128 + wid*64)*8);
        }
    };
    auto stageX_issue = [&](int k0){        // k0 >= 1024: x from fp32 input
        #pragma unroll
        for (int it=0; it<4; ++it){
            int cid = it*128 + tid;
            int row = cid>>3, kc = cid&7;
            const float4* s4 = (const float4*)(xf + ((size_t)(m0+row)*T_ + t)*IN_ + (k0 + kc*8 - 1024));
            float4 a = s4[0], b = s4[1];
            float* xr = (it==0)?xr0:(it==1)?xr1:(it==2)?xr2:xr3;
            xr[0]=a.x; xr[1]=a.y; xr[2]=a.z; xr[3]=a.w;
            xr[4]=b.x; xr[5]=b.y; xr[6]=b.z; xr[7]=b.w;
        }
    };
    auto stageX_finish = [&](int buf){
        ushort* la = As[buf];
        #pragma unroll
        for (int it=0; it<4; ++it){
            int cid = it*128 + tid;
            int row = cid>>3, kc = cid&7;
            int kcs = kc ^ (row&7);
            const float* xr = (it==0)?xr0:(it==1)?xr1:(it==2)?xr2:xr3;
            ushort t8[8];
            #pragma unroll
            for (int q=0;q<8;++q) t8[q] = bf16bits(xr[q]);
            *(ulong2*)(la + (size_t)row*64 + kcs*8) = *(ulong2*)t8;
        }
    };

    f32x4 acc[4][4] = {};
    stageA_h(0, kStart);
    stageB(0, kStart);
    __syncthreads();

    int cur = 0;
    for (int i=0; i<nIter; ++i){
        int k0n = kStart + ((i+1)<<6);
        bool more = (i+1 < nIter);
        bool nx_x = false;
        if (more){
            nx_x = (!isA) && (k0n >= 1024);
            if (nx_x) stageX_issue(k0n);
            else      stageA_h(cur^1, k0n);
            stageB(cur^1, k0n);
        }
        ushort* la = As[cur];
        ushort* lb = Bs[cur];
        #pragma unroll
        for (int kk=0; kk<2; ++kk){
            short8 af[4], bfr[4];
            #pragma unroll
            for (int mr=0;mr<4;++mr){
                int r = mr*16 + (lane&15);
                int j = (kk*4 + (lane>>4)) ^ (r&7);
                af[mr] = *(const short8*)(la + r*64 + j*8);
            }
            #pragma unroll
            for (int nr=0;nr<4;++nr){
                int r = wid*64 + nr*16 + (lane&15);
                int j = (kk*4 + (lane>>4)) ^ (r&7);
                bfr[nr] = *(const short8*)(lb + r*64 + j*8);
            }
            #pragma unroll
            for (int mr=0;mr<4;++mr)
                #pragma unroll
                for (int nr=0;nr<4;++nr)
                    acc[mr][nr] = __builtin_amdgcn_mfma_f32_16x16x32_bf16(af[mr], bfr[nr], acc[mr][nr], 0,0,0);
        }
        if (more && nx_x) stageX_finish(cur^1);
        __syncthreads();
        cur ^= 1;
    }

    float* Pg = P + ((size_t)split*11 + g)*BH_;
    #pragma unroll
    for (int mr=0;mr<4;++mr){
        #pragma unroll
        for (int nr=0;nr<4;++nr){
            int col = n0g + wid*64 + nr*16 + (lane&15);
            #pragma unroll
            for (int r=0;r<4;++r){
                int rowg = m0 + mr*16 + (lane>>4)*4 + r;
                Pg[(size_t)rowg*H_ + col] = acc[mr][nr][r];
            }
        }
    }
}

// ---- per-row: sum split-K partials -> gates -> scores -> Z -> softmax -> c,h
__global__ __launch_bounds__(1024) void step_update(
    const float* __restrict__ P, BPtrs bp,
    float* __restrict__ c, ushort* __restrict__ hb, ushort* __restrict__ cbuf,
    float* __restrict__ out, int t)
{
    int b = blockIdx.x;
    int j = threadIdx.x;
    int wid = j>>6, lane = j&63;
    const float* Pb = P + (size_t)b*H_;

    auto gp = [&](int g){
        return Pb[(size_t)g*BH_ + j] + Pb[(size_t)(11+g)*BH_ + j];
    };

    float fv = sigmf(gp(0) + bp.b[0][j]);
    float ov = sigmf(gp(1) + bp.b[1][j]);
    float lY = tanhfast(gp(2) + bp.b[2][j]) * sigmf(gp(6) + bp.b[6][j]);
    float lI = tanhfast(gp(3) + bp.b[3][j]) * sigmf(gp(7) + bp.b[7][j]);
    float lP = tanhfast(gp(4) + bp.b[4][j]) * sigmf(gp(8) + bp.b[8][j]);
    float lN = tanhfast(gp(5) + bp.b[5][j]) * sigmf(gp(9) + bp.b[9][j]);
    float cw = gp(10);

    float v0=lY*cw, v1=lI*cw, v2=lP*cw, v3=lN*cw;
    #pragma unroll
    for (int d=32; d>=1; d>>=1){
        v0 += __shfl_down(v0,d); v1 += __shfl_down(v1,d);
        v2 += __shfl_down(v2,d); v3 += __shfl_down(v3,d);
    }
    __shared__ float red[16][4];
    if (lane==0){ red[wid][0]=v0; red[wid][1]=v1; red[wid][2]=v2; red[wid][3]=v3; }
    __syncthreads();
    float sY=0, sI=0, sP=0, sN=0;
    #pragma unroll
    for (int w=0; w<16; ++w){
        sY += red[w][0]; sI += red[w][1]; sP += red[w][2]; sN += red[w][3];
    }

    float zp = __expf(tanhfast(sY + bp.bA[0][j]))
             + __expf(tanhfast(sI + bp.bA[1][j]))
             + __expf(tanhfast(sP + bp.bA[2][j]))
             + __expf(tanhfast(sN + bp.bA[3][j]));
    #pragma unroll
    for (int d=32; d>=1; d>>=1) zp += __shfl_down(zp,d);
    __shared__ float zred[16];
    if (lane==0) zred[wid] = zp;
    __syncthreads();
    float Z = 0;
    #pragma unroll
    for (int w=0; w<16; ++w) Z += zred[w];
    float Zi = 1.0f / Z;
    float a0 = __expf(tanhfast(sY + bp.bA[0][0]))*Zi;
    float a1 = __expf(tanhfast(sY + bp.bA[0][1]))*Zi;
    float a2 = __expf(tanhfast(sY + bp.bA[0][2]))*Zi;
    float a3 = __expf(tanhfast(sY + bp.bA[0][3]))*Zi;

    float lT = a0*lY + a1*lI + a2*lP + a3*lN;
    float cn = c[(size_t)b*H_ + j]*fv + lT;
    c[(size_t)b*H_ + j] = cn;
    cbuf[(size_t)b*H_ + j] = bf16bits(cn);
    float hn = tanhfast(cn)*ov;
    hb[(size_t)b*H_ + j] = bf16bits(hn);
    out[((size_t)b*T_ + t)*H_ + j] = hn;
}

extern "C" void kernel_launch(void* const* d_in, const int* in_sizes, int n_in,
                              void* d_out, int out_size, void* d_ws, size_t ws_size,
                              hipStream_t stream)
{
    WPtrs wp; BPtrs bp;
    for (int i=0;i<10;++i){ wp.W[i] = (const float*)d_in[2*i]; bp.b[i] = (const float*)d_in[2*i+1]; }
    wp.wA = (const float*)d_in[20];
    for (int i=0;i<4;++i) bp.bA[i] = (const float*)d_in[21+i];
    const float* xY = (const float*)d_in[25];
    const float* xI = (const float*)d_in[26];
    const float* xP = (const float*)d_in[27];
    const float* xN = (const float*)d_in[28];

    char* w = (char*)d_ws;
    size_t off = 0;
    ushort* Wt  = (ushort*)(w+off); off += (size_t)10*H_*C_*2;        // 31.46 MB
    ushort* wAt = (ushort*)(w+off); off += (size_t)H_*H_*2;           // 2.10 MB
    float*  P   = (float*)(w+off);  off += (size_t)22*BH_*4;          // 23.07 MB
    float*  c   = (float*)(w+off);  off += (size_t)BH_*4;             // 1 MB
    ushort* hb  = (ushort*)(w+off); off += (size_t)BH_*2;             // 0.5 MB
    ushort* cbuf= (ushort*)(w+off); off += (size_t)BH_*2;             // 0.5 MB
    // total ~58.6 MB

    // zero c (fp32) + hb + cbuf (contiguous 8*BH_ bytes)
    hipMemsetAsync(c, 0, (size_t)BH_*8, stream);

    transpose_w<<<dim3(C_/32, H_/32, 11), dim3(32,8), 0, stream>>>(wp, Wt, wAt);

    float* out = (float*)d_out;
    for (int t=0;t<T_;++t){
        gemm_step<<<704, 128, 0, stream>>>(Wt, wAt, xY, xI, xP, xN, hb, cbuf, P, t);
        step_update<<<B_, 1024, 0, stream>>>(P, bp, c, hb, cbuf, out, t);
    }
}